// Round 9
// baseline (316.966 us; speedup 1.0000x reference)
//
#include <hip/hip_runtime.h>
#include <hip/hip_bf16.h>
#include <type_traits>

#define N_SUP 32768
#define M_Q 32768
#define H_NB 32
#define K_PTS 15
#define CIN 64
#define COUT 64
#define SIGMA_ 0.1f
#define NGROUPS 8
#define NEG_SLOPE_ 0.1f
#define GEPS 1e-5f

#define QPB 16    // queries per block (4 per wave)
#define NWAVES 4
#define KSP 15    // MFMA K-steps per pass: 15 kpoints x 32ch (=K 480)

typedef __attribute__((ext_vector_type(8))) short bf16x8;
typedef __attribute__((ext_vector_type(4))) float f32x4;
typedef __attribute__((ext_vector_type(2))) float f32x2;

__device__ __forceinline__ unsigned short f_to_bf16(float f) {
    unsigned int x = __builtin_bit_cast(unsigned int, f);
    unsigned int r = (x + 0x7fffu + ((x >> 16) & 1u)) >> 16;
    return (unsigned short)r;
}

// ---- prep 1: bf16 split-channel table [2][N][32] + per-row validity ----
__global__ __launch_bounds__(256) void prep_feats_valid_kernel(
    const float* __restrict__ s_feats, unsigned short* __restrict__ featsbf,
    float* __restrict__ valid)
{
    const int row  = blockIdx.x * 4 + (threadIdx.x >> 6);
    const int lane = threadIdx.x & 63;
    float f = s_feats[row * CIN + lane];
    __builtin_nontemporal_store(f_to_bf16(f),
        &featsbf[(size_t)(lane >> 5) * (N_SUP * 32) + row * 32 + (lane & 31)]);
#pragma unroll
    for (int m = 1; m < 64; m <<= 1) f += __shfl_xor(f, m, 64);
    if (lane == 0) valid[row] = (f > 0.f) ? 1.f : 0.f;
}

__global__ __launch_bounds__(256) void prep_valid_kernel(
    const float* __restrict__ s_feats, float* __restrict__ valid)
{
    const int row  = blockIdx.x * 4 + (threadIdx.x >> 6);
    const int lane = threadIdx.x & 63;
    float f = s_feats[row * CIN + lane];
#pragma unroll
    for (int m = 1; m < 64; m <<= 1) f += __shfl_xor(f, m, 64);
    if (lane == 0) valid[row] = (f > 0.f) ? 1.f : 0.f;
}

// ---- prep 1b: per-query reciprocal neighbor count ----
__global__ __launch_bounds__(256) void prep_cnt_kernel(
    const int* __restrict__ nbr, const float* __restrict__ valid,
    float* __restrict__ rcnt)
{
    const int w = threadIdx.x >> 6, lane = threadIdx.x & 63;
    const int m = blockIdx.x * 8 + w * 2 + (lane >> 5);
    const int h = lane & 31;
    float v = valid[__builtin_nontemporal_load(&nbr[m * H_NB + h])];
#pragma unroll
    for (int msk = 1; msk < 32; msk <<= 1) v += __shfl_xor(v, msk, 64);
    if (h == 0) rcnt[m] = 1.f / fmaxf(v, 1.f);
}

// ---- prep 2: pack weights into per-pass bf16 B-fragments ----
__global__ __launch_bounds__(256) void prep_wpack_kernel(
    const float* __restrict__ weights, unsigned short* __restrict__ wpack)
{
    const int t = blockIdx.x * 256 + threadIdx.x;
    if (t >= 2 * NWAVES * KSP * 64) return;
    const int l  = t & 63;
    const int s  = (t >> 6) % KSP;
    const int wt = ((t >> 6) / KSP) % NWAVES;
    const int p  = t / (64 * KSP * NWAVES);
    const int d  = wt * 16 + (l & 15);
    unsigned short v[8];
#pragma unroll
    for (int j = 0; j < 8; ++j) {
        const int c = p * 32 + ((l >> 4) << 3) + j;
        v[j] = f_to_bf16(weights[(s * CIN + c) * COUT + d]);
    }
    uint4 u;
    u.x = (unsigned)v[0] | ((unsigned)v[1] << 16);
    u.y = (unsigned)v[2] | ((unsigned)v[3] << 16);
    u.z = (unsigned)v[4] | ((unsigned)v[5] << 16);
    u.w = (unsigned)v[6] | ((unsigned)v[7] << 16);
    *(uint4*)&wpack[t * 8] = u;
}

// ---- conv pass kernel: channel slice P (32 ch), half the K dimension ----
template <int P, bool BF, bool LAST>
__global__ __launch_bounds__(256) void kpconv_pass(
    const float* __restrict__ s_feats,
    const unsigned short* __restrict__ featsbf,
    const float* __restrict__ q_points,
    const float* __restrict__ s_points,
    const int*   __restrict__ nbr_idx,
    const float* __restrict__ kpts,
    const unsigned short* __restrict__ wpack,
    const float* __restrict__ rcnt,
    const float* __restrict__ bias,
    float* __restrict__ y_out,
    float* __restrict__ gstats)
{
    __shared__ float w_lds[NWAVES][H_NB][16];            // 8 KB
    __shared__ unsigned short wtd_lds[QPB][K_PTS][32];   // 15 KB (q-chunk swizzled)
    __shared__ float nbr_lds[QPB];

    const int tid  = threadIdx.x;
    const int lane = tid & 63;
    const int wid  = __builtin_amdgcn_readfirstlane(tid >> 6);

    float kpx[K_PTS], kpy[K_PTS], kpz[K_PTS];
#pragma unroll
    for (int k = 0; k < K_PTS; ++k) {
        kpx[k] = kpts[k * 3 + 0];
        kpy[k] = kpts[k * 3 + 1];
        kpz[k] = kpts[k * 3 + 2];
    }

    const int h1    = lane >> 1;   // 2 lanes per neighbor in the idx row
    const int khalf = lane & 1;
    const int hgrp  = lane >> 4;   // h mod 4 group
    const int cpair = lane & 15;   // ch-pair within the 32-ch slice
    const int mbase = blockIdx.x * QPB + wid * 4;

    // ---- prologue: all per-query geometry up front ----
    int h1i[4];
#pragma unroll
    for (int j = 0; j < 4; ++j)
        h1i[j] = __builtin_nontemporal_load(&nbr_idx[(mbase + j) * H_NB + h1]);
    float ddx[4], ddy[4], ddz[4];
#pragma unroll
    for (int j = 0; j < 4; ++j) {
        const float qx = q_points[(mbase + j) * 3 + 0];
        const float qy = q_points[(mbase + j) * 3 + 1];
        const float qz = q_points[(mbase + j) * 3 + 2];
        ddx[j] = s_points[h1i[j] * 3 + 0] - qx;
        ddy[j] = s_points[h1i[j] * 3 + 1] - qy;
        ddz[j] = s_points[h1i[j] * 3 + 2] - qz;
    }

    using fbuf_t = typename std::conditional<BF, unsigned int, f32x2>::type;
    fbuf_t fb0[8], fb1[8], fb2[8], fb3[8];

    // gather 8 instr/query; instr t covers h = 4t + hgrp
    auto issueF = [&](int j, fbuf_t (&fb)[8]) {
#pragma unroll
        for (int t = 0; t < 8; ++t) {
            const int sidx = __shfl(h1i[j], 8 * t + 2 * hgrp, 64);
            if constexpr (BF)
                fb[t] = *(const unsigned int*)
                    &featsbf[(size_t)P * (N_SUP * 32) + sidx * 32 + cpair * 2];
            else
                fb[t] = *(const f32x2*)&s_feats[sidx * CIN + P * 32 + cpair * 2];
        }
    };

    // compute correlation weights into REGISTERS (overlaps gather latency)
    auto wcompr = [&](int j, float (&wr)[8]) {
#pragma unroll
        for (int jj = 0; jj < 8; ++jj) {
            const int k = khalf * 8 + jj;
            float w = 0.f;
            if (k < K_PTS) {
                const float ex = ddx[j] - kpx[k];
                const float ey = ddy[j] - kpy[k];
                const float ez = ddz[j] - kpz[k];
                w = fmaxf(1.f - sqrtf(ex * ex + ey * ey + ez * ez) * (1.f / SIGMA_), 0.f);
            }
            wr[jj] = w;
        }
    };

    auto wstore = [&](float (&wr)[8]) {
        *(float4*)&w_lds[wid][h1][khalf * 8 + 0] = make_float4(wr[0], wr[1], wr[2], wr[3]);
        *(float4*)&w_lds[wid][h1][khalf * 8 + 4] = make_float4(wr[4], wr[5], wr[6], wr[7]);
    };

    auto consume = [&](int j, fbuf_t (&fb)[8]) {
        const int q = wid * 4 + j;
        f32x2 acc[K_PTS];
#pragma unroll
        for (int k = 0; k < K_PTS; ++k) acc[k] = (f32x2){0.f, 0.f};
#pragma unroll
        for (int t = 0; t < 8; ++t) {
            f32x2 fv;
            if constexpr (BF) {
                const unsigned int u = fb[t];
                fv.x = __builtin_bit_cast(float, u << 16);
                fv.y = __builtin_bit_cast(float, u & 0xffff0000u);
            } else {
                fv = fb[t];
            }
            const int hh = 4 * t + hgrp;
            const float4 w0 = *(const float4*)&w_lds[wid][hh][0];
            const float4 w1 = *(const float4*)&w_lds[wid][hh][4];
            const float4 w2 = *(const float4*)&w_lds[wid][hh][8];
            const float4 w3 = *(const float4*)&w_lds[wid][hh][12];
            acc[0]  += fv * w0.x;  acc[1]  += fv * w0.y;
            acc[2]  += fv * w0.z;  acc[3]  += fv * w0.w;
            acc[4]  += fv * w1.x;  acc[5]  += fv * w1.y;
            acc[6]  += fv * w1.z;  acc[7]  += fv * w1.w;
            acc[8]  += fv * w2.x;  acc[9]  += fv * w2.y;
            acc[10] += fv * w2.z;  acc[11] += fv * w2.w;
            acc[12] += fv * w3.x;  acc[13] += fv * w3.y;
            acc[14] += fv * w3.z;
        }
#pragma unroll
        for (int k = 0; k < K_PTS; ++k) {
            acc[k].x += __shfl_xor(acc[k].x, 16, 64);
            acc[k].y += __shfl_xor(acc[k].y, 16, 64);
            acc[k].x += __shfl_xor(acc[k].x, 32, 64);
            acc[k].y += __shfl_xor(acc[k].y, 32, 64);
        }
        const int cin_sl = cpair * 2;                       // 0..31
        const int cswz = ((((cin_sl >> 3) ^ (q & 3)) << 3)) | (cin_sl & 7);
#pragma unroll
        for (int k = 0; k < K_PTS; ++k) {
            if ((k & 3) == hgrp) {
                unsigned int u;
                asm("v_cvt_pk_bf16_f32 %0, %1, %2"
                    : "=v"(u) : "v"(acc[k].x), "v"(acc[k].y));
                *(unsigned int*)&wtd_lds[q][k][cswz] = u;
            }
        }
        if (LAST && lane == 0) nbr_lds[q] = rcnt[mbase + j];
    };

    // ---- deep pipeline: 32 gathers in flight, w computed under them ----
    issueF(0, fb0); issueF(1, fb1); issueF(2, fb2); issueF(3, fb3);
    float wr0[8], wr1[8], wr2[8], wr3[8];
    wcompr(0, wr0); wcompr(1, wr1); wcompr(2, wr2); wcompr(3, wr3);
    wstore(wr0); consume(0, fb0);
    wstore(wr1); consume(1, fb1);
    wstore(wr2); consume(2, fb2);
    wstore(wr3); consume(3, fb3);
    __syncthreads();

    // ---- MFMA: out16x64 += wtd[16q x (15k*32c)] * Wslice ----
    {
        const int qa  = lane & 15;
        const int grp = lane >> 4;
        const unsigned short* wp =
            &wpack[(((P * NWAVES + wid) * KSP) * 64 + lane) * 8];
        // burst-load all 15 B-fragments (independent; one latency exposure)
        bf16x8 bfr[15];
#pragma unroll
        for (int s = 0; s < KSP; ++s)
            bfr[s] = *(const bf16x8*)&wp[s * 512];
        f32x4 acc3 = {0.f, 0.f, 0.f, 0.f};
        const int ch = grp ^ (qa & 3);   // un-swizzle chunk
#pragma unroll
        for (int s = 0; s < KSP; ++s) {
            bf16x8 a = *(const bf16x8*)&wtd_lds[qa][s][ch * 8];
            acc3 = __builtin_amdgcn_mfma_f32_16x16x32_bf16(a, bfr[s], acc3, 0, 0, 0);
        }
        // C layout: col(d)=lane&15, row(q)=grp*4+r
        const int dl = wid * 16 + (lane & 15);
        if constexpr (!LAST) {
#pragma unroll
            for (int r = 0; r < 4; ++r) {
                const int qq = grp * 4 + r;
                __builtin_nontemporal_store(acc3[r],
                    &y_out[(blockIdx.x * QPB + qq) * COUT + dl]);
            }
        } else {
            const float bv = bias[dl];
            float s1 = 0.f, s2 = 0.f;
            float part[4];
#pragma unroll
            for (int r = 0; r < 4; ++r)
                part[r] = __builtin_nontemporal_load(
                    &y_out[(blockIdx.x * QPB + grp * 4 + r) * COUT + dl]);
#pragma unroll
            for (int r = 0; r < 4; ++r) {
                const int qq = grp * 4 + r;
                const int gi = (blockIdx.x * QPB + qq) * COUT + dl;
                const float yv = (acc3[r] + part[r]) * nbr_lds[qq] + bv;
                __builtin_nontemporal_store(yv, &y_out[gi]);
                s1 += yv;
                s2 += yv * yv;
            }
            s1 += __shfl_xor(s1, 1, 64);   s2 += __shfl_xor(s2, 1, 64);
            s1 += __shfl_xor(s1, 2, 64);   s2 += __shfl_xor(s2, 2, 64);
            s1 += __shfl_xor(s1, 4, 64);   s2 += __shfl_xor(s2, 4, 64);
            s1 += __shfl_xor(s1, 16, 64);  s2 += __shfl_xor(s2, 16, 64);
            s1 += __shfl_xor(s1, 32, 64);  s2 += __shfl_xor(s2, 32, 64);
            if (lane == 0 || lane == 8) {
                const int g = wid * 2 + ((lane >> 3) & 1);
                atomicAdd(&gstats[g], s1);
                atomicAdd(&gstats[8 + g], s2);
            }
        }
    }
}

__global__ __launch_bounds__(256) void gn_kernel(
    const float* __restrict__ gstats,
    const float* __restrict__ gamma,
    const float* __restrict__ beta,
    float* __restrict__ out)
{
    const int idx4 = blockIdx.x * blockDim.x + threadIdx.x;
    const int d4 = idx4 & (COUT / 4 - 1);
    const int d = d4 * 4;
    const int g = d >> 3;
    const float cntinv = 1.f / (float)(M_Q * (COUT / NGROUPS));
    const float mean = gstats[g] * cntinv;
    const float var = gstats[8 + g] * cntinv - mean * mean;
    const float rs = rsqrtf(var + GEPS);
    f32x4 y = __builtin_nontemporal_load((const f32x4*)out + idx4);
    const float4 gm = ((const float4*)gamma)[d4];
    const float4 bt = ((const float4*)beta)[d4];
    float v;
    v = (y.x - mean) * rs * gm.x + bt.x;  y.x = v >= 0.f ? v : NEG_SLOPE_ * v;
    v = (y.y - mean) * rs * gm.y + bt.y;  y.y = v >= 0.f ? v : NEG_SLOPE_ * v;
    v = (y.z - mean) * rs * gm.z + bt.z;  y.z = v >= 0.f ? v : NEG_SLOPE_ * v;
    v = (y.w - mean) * rs * gm.w + bt.w;  y.w = v >= 0.f ? v : NEG_SLOPE_ * v;
    __builtin_nontemporal_store(y, (f32x4*)out + idx4);
}

extern "C" void kernel_launch(void* const* d_in, const int* in_sizes, int n_in,
                              void* d_out, int out_size, void* d_ws, size_t ws_size,
                              hipStream_t stream) {
    const float* s_feats  = (const float*)d_in[0];
    const float* q_points = (const float*)d_in[1];
    const float* s_points = (const float*)d_in[2];
    const int*   nbr      = (const int*)d_in[3];
    const float* kpts     = (const float*)d_in[4];
    const float* weights  = (const float*)d_in[5];
    const float* bias     = (const float*)d_in[6];
    const float* gamma    = (const float*)d_in[7];
    const float* beta     = (const float*)d_in[8];
    float* out = (float*)d_out;

    // ws: stats[16] | valid[N] | rcnt[M] | wpack (2*4*15*64*8 ush) | featsbf [2][N][32]
    float* stats = (float*)d_ws;
    float* valid = stats + 16;
    float* rcnt  = valid + N_SUP;
    unsigned short* wpack = (unsigned short*)(rcnt + M_Q);        // 61440 ush
    unsigned short* featsbf = wpack + 2 * NWAVES * KSP * 64 * 8;  // 2M ush
    const size_t need_bf = (size_t)((16 + N_SUP + M_Q) * 4)
                         + (size_t)(2 * NWAVES * KSP * 64 * 8 * 2)
                         + (size_t)N_SUP * CIN * 2;
    const bool use_bf = ws_size >= need_bf;

    hipMemsetAsync(stats, 0, 16 * sizeof(float), stream);
    if (use_bf)
        prep_feats_valid_kernel<<<N_SUP / 4, 256, 0, stream>>>(s_feats, featsbf, valid);
    else
        prep_valid_kernel<<<N_SUP / 4, 256, 0, stream>>>(s_feats, valid);
    prep_cnt_kernel<<<M_Q / 8, 256, 0, stream>>>(nbr, valid, rcnt);
    prep_wpack_kernel<<<(2 * NWAVES * KSP * 64 + 255) / 256, 256, 0, stream>>>(weights, wpack);

    const int grid = M_Q / QPB;
    if (use_bf) {
        kpconv_pass<0, true, false><<<grid, 256, 0, stream>>>(
            s_feats, featsbf, q_points, s_points, nbr, kpts, wpack, rcnt, bias, out, stats);
        kpconv_pass<1, true, true><<<grid, 256, 0, stream>>>(
            s_feats, featsbf, q_points, s_points, nbr, kpts, wpack, rcnt, bias, out, stats);
    } else {
        kpconv_pass<0, false, false><<<grid, 256, 0, stream>>>(
            s_feats, featsbf, q_points, s_points, nbr, kpts, wpack, rcnt, bias, out, stats);
        kpconv_pass<1, false, true><<<grid, 256, 0, stream>>>(
            s_feats, featsbf, q_points, s_points, nbr, kpts, wpack, rcnt, bias, out, stats);
    }
    gn_kernel<<<(M_Q * COUT / 4) / 256, 256, 0, stream>>>(stats, gamma, beta, out);
}

// Round 10
// 277.514 us; speedup vs baseline: 1.1422x; 1.1422x over previous
//
#include <hip/hip_runtime.h>
#include <hip/hip_bf16.h>
#include <type_traits>

#define N_SUP 32768
#define M_Q 32768
#define H_NB 32
#define K_PTS 15
#define CIN 64
#define COUT 64
#define SIGMA_ 0.1f
#define NGROUPS 8
#define NEG_SLOPE_ 0.1f
#define GEPS 1e-5f

#define QPB 16    // queries per block (4 per wave)
#define NWAVES 4
#define KSP 15    // MFMA-2 K-steps per pass: 15 kpoints x 32ch

typedef __attribute__((ext_vector_type(8))) short bf16x8;
typedef __attribute__((ext_vector_type(4))) short bf16x4;
typedef __attribute__((ext_vector_type(4))) float f32x4;
typedef __attribute__((ext_vector_type(2))) float f32x2;

__device__ __forceinline__ unsigned short f_to_bf16(float f) {
    unsigned int x = __builtin_bit_cast(unsigned int, f);
    unsigned int r = (x + 0x7fffu + ((x >> 16) & 1u)) >> 16;
    return (unsigned short)r;
}

// ---- prep 1: bf16 split-channel table [2][N][32] + per-row validity ----
__global__ __launch_bounds__(256) void prep_feats_valid_kernel(
    const float* __restrict__ s_feats, unsigned short* __restrict__ featsbf,
    float* __restrict__ valid)
{
    const int row  = blockIdx.x * 4 + (threadIdx.x >> 6);
    const int lane = threadIdx.x & 63;
    float f = s_feats[row * CIN + lane];
    __builtin_nontemporal_store(f_to_bf16(f),
        &featsbf[(size_t)(lane >> 5) * (N_SUP * 32) + row * 32 + (lane & 31)]);
#pragma unroll
    for (int m = 1; m < 64; m <<= 1) f += __shfl_xor(f, m, 64);
    if (lane == 0) valid[row] = (f > 0.f) ? 1.f : 0.f;
}

__global__ __launch_bounds__(256) void prep_valid_kernel(
    const float* __restrict__ s_feats, float* __restrict__ valid)
{
    const int row  = blockIdx.x * 4 + (threadIdx.x >> 6);
    const int lane = threadIdx.x & 63;
    float f = s_feats[row * CIN + lane];
#pragma unroll
    for (int m = 1; m < 64; m <<= 1) f += __shfl_xor(f, m, 64);
    if (lane == 0) valid[row] = (f > 0.f) ? 1.f : 0.f;
}

// ---- prep 1b: per-query reciprocal neighbor count ----
__global__ __launch_bounds__(256) void prep_cnt_kernel(
    const int* __restrict__ nbr, const float* __restrict__ valid,
    float* __restrict__ rcnt)
{
    const int w = threadIdx.x >> 6, lane = threadIdx.x & 63;
    const int m = blockIdx.x * 8 + w * 2 + (lane >> 5);
    const int h = lane & 31;
    float v = valid[__builtin_nontemporal_load(&nbr[m * H_NB + h])];
#pragma unroll
    for (int msk = 1; msk < 32; msk <<= 1) v += __shfl_xor(v, msk, 64);
    if (h == 0) rcnt[m] = 1.f / fmaxf(v, 1.f);
}

// ---- prep 2: pack weights into per-pass bf16 B-fragments ----
// B2[k = kp-step s, elem c][n = d]: lane l elem j = W[s][c=p*32+(l>>4)*8+j][d=wt*16+(l&15)]
__global__ __launch_bounds__(256) void prep_wpack_kernel(
    const float* __restrict__ weights, unsigned short* __restrict__ wpack)
{
    const int t = blockIdx.x * 256 + threadIdx.x;
    if (t >= 2 * NWAVES * KSP * 64) return;
    const int l  = t & 63;
    const int s  = (t >> 6) % KSP;
    const int wt = ((t >> 6) / KSP) % NWAVES;
    const int p  = t / (64 * KSP * NWAVES);
    const int d  = wt * 16 + (l & 15);
    unsigned short v[8];
#pragma unroll
    for (int j = 0; j < 8; ++j) {
        const int c = p * 32 + ((l >> 4) << 3) + j;
        v[j] = f_to_bf16(weights[(s * CIN + c) * COUT + d]);
    }
    uint4 u;
    u.x = (unsigned)v[0] | ((unsigned)v[1] << 16);
    u.y = (unsigned)v[2] | ((unsigned)v[3] << 16);
    u.z = (unsigned)v[4] | ((unsigned)v[5] << 16);
    u.w = (unsigned)v[6] | ((unsigned)v[7] << 16);
    *(uint4*)&wpack[t * 8] = u;
}

// ---- conv pass kernel: channel slice P (32 ch), half the K dimension ----
// Phase 2 is now MFMA-1 per query: wtd[16kp x 32c] = w[16kp x 32h] * f[32h x 32c]
template <int P, bool BF, bool LAST>
__global__ __launch_bounds__(256) void kpconv_pass(
    const float* __restrict__ s_feats,
    const unsigned short* __restrict__ featsbf,
    const float* __restrict__ q_points,
    const float* __restrict__ s_points,
    const int*   __restrict__ nbr_idx,
    const float* __restrict__ kpts,
    const unsigned short* __restrict__ wpack,
    const float* __restrict__ rcnt,
    const float* __restrict__ bias,
    float* __restrict__ y_out,
    float* __restrict__ gstats)
{
    // per-wave slabs; rows padded to 36 ush (72 B, 8B-aligned for ds_read_b64)
    __shared__ __align__(16) unsigned short flds[NWAVES][32][36];  // [c][h] 9.2 KB
    __shared__ __align__(16) unsigned short wb[NWAVES][16][36];    // [kp][h] 4.6 KB
    __shared__ __align__(16) unsigned short wtd_lds[QPB][K_PTS][32]; // 15 KB, q-swz
    __shared__ float nbr_lds[QPB];

    const int tid  = threadIdx.x;
    const int lane = tid & 63;
    const int wid  = __builtin_amdgcn_readfirstlane(tid >> 6);

    float kpx[K_PTS], kpy[K_PTS], kpz[K_PTS];
#pragma unroll
    for (int k = 0; k < K_PTS; ++k) {
        kpx[k] = kpts[k * 3 + 0];
        kpy[k] = kpts[k * 3 + 1];
        kpz[k] = kpts[k * 3 + 2];
    }

    const int h1    = lane >> 1;   // lane 2h(+0/1) owns neighbor h
    const int khalf = lane & 1;
    const int hgrp  = lane >> 4;   // gather: row group
    const int cpair = lane & 15;   // gather: ch-pair within 32-ch slice
    const int mbase = blockIdx.x * QPB + wid * 4;

    // ---- prologue: geometry ----
    int h1i[4];
#pragma unroll
    for (int j = 0; j < 4; ++j)
        h1i[j] = __builtin_nontemporal_load(&nbr_idx[(mbase + j) * H_NB + h1]);
    float ddx[4], ddy[4], ddz[4];
#pragma unroll
    for (int j = 0; j < 4; ++j) {
        const float qx = q_points[(mbase + j) * 3 + 0];
        const float qy = q_points[(mbase + j) * 3 + 1];
        const float qz = q_points[(mbase + j) * 3 + 2];
        ddx[j] = s_points[h1i[j] * 3 + 0] - qx;
        ddy[j] = s_points[h1i[j] * 3 + 1] - qy;
        ddz[j] = s_points[h1i[j] * 3 + 2] - qz;
    }
    if (LAST && lane < 4) nbr_lds[wid * 4 + lane] = rcnt[mbase + lane];

    using fbuf_t = typename std::conditional<BF, unsigned int, f32x2>::type;
    fbuf_t fbA[8], fbB[8];

    // gather 8 instr/query; instr t covers rows h = 4t + hgrp, 64 B each
    auto issueG = [&](int j, fbuf_t (&fb)[8]) {
#pragma unroll
        for (int t = 0; t < 8; ++t) {
            const int sidx = __shfl(h1i[j], 8 * t + 2 * hgrp, 64);
            if constexpr (BF)
                fb[t] = *(const unsigned int*)
                    &featsbf[(size_t)P * (N_SUP * 32) + sidx * 32 + cpair * 2];
            else
                fb[t] = *(const f32x2*)&s_feats[sidx * CIN + P * 32 + cpair * 2];
        }
    };

    // compute w (bf16) into wb[wid]: covers kp 0..15, row 15 zeroed
    auto wstore = [&](int j) {
#pragma unroll
        for (int jj = 0; jj < 8; ++jj) {
            const int k = khalf * 8 + jj;
            float w = 0.f;
            if (k < K_PTS) {
                const float ex = ddx[j] - kpx[k];
                const float ey = ddy[j] - kpy[k];
                const float ez = ddz[j] - kpz[k];
                w = fmaxf(1.f - sqrtf(ex * ex + ey * ey + ez * ez) * (1.f / SIGMA_), 0.f);
            }
            wb[wid][k][h1] = f_to_bf16(w);
        }
    };

    // transpose-write gathered rows into flds[wid][c][h]
    auto fwrite = [&](fbuf_t (&fb)[8]) {
#pragma unroll
        for (int t = 0; t < 8; ++t) {
            const int h = 4 * t + hgrp;
            unsigned short lo, hi;
            if constexpr (BF) {
                lo = (unsigned short)(fb[t] & 0xffffu);
                hi = (unsigned short)(fb[t] >> 16);
            } else {
                lo = f_to_bf16(fb[t].x);
                hi = f_to_bf16(fb[t].y);
            }
            flds[wid][cpair * 2 + 0][h] = lo;
            flds[wid][cpair * 2 + 1][h] = hi;
        }
    };

    // MFMA-1: wtd[16kp x 32c] = wb[16kp x 32h] * flds[32h x 32c], write swizzled
    auto mfma1 = [&](int j) {
        const int q   = wid * 4 + j;
        const int m16 = lane & 15;        // A row (kp) / B,D col
        const int g8  = (lane >> 4) * 8;  // k-offset (h)
        const bf16x4 alo = *(const bf16x4*)&wb[wid][m16][g8];
        const bf16x4 ahi = *(const bf16x4*)&wb[wid][m16][g8 + 4];
        const bf16x8 a = {alo[0], alo[1], alo[2], alo[3],
                          ahi[0], ahi[1], ahi[2], ahi[3]};
        f32x4 d0 = {0.f, 0.f, 0.f, 0.f}, d1 = {0.f, 0.f, 0.f, 0.f};
        {
            const bf16x4 blo = *(const bf16x4*)&flds[wid][m16][g8];
            const bf16x4 bhi = *(const bf16x4*)&flds[wid][m16][g8 + 4];
            const bf16x8 b = {blo[0], blo[1], blo[2], blo[3],
                              bhi[0], bhi[1], bhi[2], bhi[3]};
            d0 = __builtin_amdgcn_mfma_f32_16x16x32_bf16(a, b, d0, 0, 0, 0);
        }
        {
            const bf16x4 blo = *(const bf16x4*)&flds[wid][16 + m16][g8];
            const bf16x4 bhi = *(const bf16x4*)&flds[wid][16 + m16][g8 + 4];
            const bf16x8 b = {blo[0], blo[1], blo[2], blo[3],
                              bhi[0], bhi[1], bhi[2], bhi[3]};
            d1 = __builtin_amdgcn_mfma_f32_16x16x32_bf16(a, b, d1, 0, 0, 0);
        }
        // D layout: col(c)=lane&15, row(kp)=(lane>>4)*4+r ; store q-swizzled
#pragma unroll
        for (int r = 0; r < 4; ++r) {
            const int kp = (lane >> 4) * 4 + r;
            if (kp < K_PTS) {
                const int c0 = m16;
                const int s0 = ((((c0 >> 3) ^ (q & 3)) << 3)) | (c0 & 7);
                wtd_lds[q][kp][s0] = f_to_bf16(d0[r]);
                const int c1 = 16 + m16;
                const int s1 = ((((c1 >> 3) ^ (q & 3)) << 3)) | (c1 & 7);
                wtd_lds[q][kp][s1] = f_to_bf16(d1[r]);
            }
        }
    };

    // ---- per-query pipeline: gather(j+1) issued under mfma1(j) ----
    issueG(0, fbA);
    wstore(0); issueG(1, fbB); fwrite(fbA); mfma1(0);
    wstore(1); issueG(2, fbA); fwrite(fbB); mfma1(1);
    wstore(2); issueG(3, fbB); fwrite(fbA); mfma1(2);
    wstore(3);                 fwrite(fbB); mfma1(3);
    __syncthreads();

    // ---- MFMA-2: out[16q x 64d] += wtd[16q x 480] * Wslice ----
    {
        const int qa  = lane & 15;
        const int grp = lane >> 4;
        const unsigned short* wp =
            &wpack[(((P * NWAVES + wid) * KSP) * 64 + lane) * 8];
        const int dl = wid * 16 + qa;
        float part[4];
        if constexpr (LAST) {
#pragma unroll
            for (int r = 0; r < 4; ++r)
                part[r] = y_out[(blockIdx.x * QPB + grp * 4 + r) * COUT + dl];
        }
        f32x4 acc3 = {0.f, 0.f, 0.f, 0.f};
        const int ch = grp ^ (qa & 3);   // un-swizzle chunk
        bf16x8 bfr0[8];
#pragma unroll
        for (int s = 0; s < 8; ++s)
            bfr0[s] = *(const bf16x8*)&wp[s * 512];
#pragma unroll
        for (int s = 0; s < 8; ++s) {
            bf16x8 a = *(const bf16x8*)&wtd_lds[qa][s][ch * 8];
            acc3 = __builtin_amdgcn_mfma_f32_16x16x32_bf16(a, bfr0[s], acc3, 0, 0, 0);
        }
        bf16x8 bfr1[7];
#pragma unroll
        for (int s = 0; s < 7; ++s)
            bfr1[s] = *(const bf16x8*)&wp[(8 + s) * 512];
#pragma unroll
        for (int s = 0; s < 7; ++s) {
            bf16x8 a = *(const bf16x8*)&wtd_lds[qa][8 + s][ch * 8];
            acc3 = __builtin_amdgcn_mfma_f32_16x16x32_bf16(a, bfr1[s], acc3, 0, 0, 0);
        }
        if constexpr (!LAST) {
#pragma unroll
            for (int r = 0; r < 4; ++r) {
                const int qq = grp * 4 + r;
                __builtin_nontemporal_store(acc3[r],
                    &y_out[(blockIdx.x * QPB + qq) * COUT + dl]);
            }
        } else {
            const float bv = bias[dl];
            float s1 = 0.f, s2 = 0.f;
#pragma unroll
            for (int r = 0; r < 4; ++r) {
                const int qq = grp * 4 + r;
                const int gi = (blockIdx.x * QPB + qq) * COUT + dl;
                const float yv = (acc3[r] + part[r]) * nbr_lds[qq] + bv;
                __builtin_nontemporal_store(yv, &y_out[gi]);
                s1 += yv;
                s2 += yv * yv;
            }
            s1 += __shfl_xor(s1, 1, 64);   s2 += __shfl_xor(s2, 1, 64);
            s1 += __shfl_xor(s1, 2, 64);   s2 += __shfl_xor(s2, 2, 64);
            s1 += __shfl_xor(s1, 4, 64);   s2 += __shfl_xor(s2, 4, 64);
            s1 += __shfl_xor(s1, 16, 64);  s2 += __shfl_xor(s2, 16, 64);
            s1 += __shfl_xor(s1, 32, 64);  s2 += __shfl_xor(s2, 32, 64);
            if (lane == 0 || lane == 8) {
                const int g = wid * 2 + ((lane >> 3) & 1);
                atomicAdd(&gstats[g], s1);
                atomicAdd(&gstats[8 + g], s2);
            }
        }
    }
}

__global__ __launch_bounds__(256) void gn_kernel(
    const float* __restrict__ gstats,
    const float* __restrict__ gamma,
    const float* __restrict__ beta,
    float* __restrict__ out)
{
    const int idx4 = blockIdx.x * blockDim.x + threadIdx.x;
    const int d4 = idx4 & (COUT / 4 - 1);
    const int d = d4 * 4;
    const int g = d >> 3;
    const float cntinv = 1.f / (float)(M_Q * (COUT / NGROUPS));
    const float mean = gstats[g] * cntinv;
    const float var = gstats[8 + g] * cntinv - mean * mean;
    const float rs = rsqrtf(var + GEPS);
    f32x4 y = __builtin_nontemporal_load((const f32x4*)out + idx4);
    const float4 gm = ((const float4*)gamma)[d4];
    const float4 bt = ((const float4*)beta)[d4];
    float v;
    v = (y.x - mean) * rs * gm.x + bt.x;  y.x = v >= 0.f ? v : NEG_SLOPE_ * v;
    v = (y.y - mean) * rs * gm.y + bt.y;  y.y = v >= 0.f ? v : NEG_SLOPE_ * v;
    v = (y.z - mean) * rs * gm.z + bt.z;  y.z = v >= 0.f ? v : NEG_SLOPE_ * v;
    v = (y.w - mean) * rs * gm.w + bt.w;  y.w = v >= 0.f ? v : NEG_SLOPE_ * v;
    __builtin_nontemporal_store(y, (f32x4*)out + idx4);
}

extern "C" void kernel_launch(void* const* d_in, const int* in_sizes, int n_in,
                              void* d_out, int out_size, void* d_ws, size_t ws_size,
                              hipStream_t stream) {
    const float* s_feats  = (const float*)d_in[0];
    const float* q_points = (const float*)d_in[1];
    const float* s_points = (const float*)d_in[2];
    const int*   nbr      = (const int*)d_in[3];
    const float* kpts     = (const float*)d_in[4];
    const float* weights  = (const float*)d_in[5];
    const float* bias     = (const float*)d_in[6];
    const float* gamma    = (const float*)d_in[7];
    const float* beta     = (const float*)d_in[8];
    float* out = (float*)d_out;

    // ws: stats[16] | valid[N] | rcnt[M] | wpack (2*4*15*64*8 ush) | featsbf [2][N][32]
    float* stats = (float*)d_ws;
    float* valid = stats + 16;
    float* rcnt  = valid + N_SUP;
    unsigned short* wpack = (unsigned short*)(rcnt + M_Q);        // 61440 ush
    unsigned short* featsbf = wpack + 2 * NWAVES * KSP * 64 * 8;  // 2M ush
    const size_t need_bf = (size_t)((16 + N_SUP + M_Q) * 4)
                         + (size_t)(2 * NWAVES * KSP * 64 * 8 * 2)
                         + (size_t)N_SUP * CIN * 2;
    const bool use_bf = ws_size >= need_bf;

    hipMemsetAsync(stats, 0, 16 * sizeof(float), stream);
    if (use_bf)
        prep_feats_valid_kernel<<<N_SUP / 4, 256, 0, stream>>>(s_feats, featsbf, valid);
    else
        prep_valid_kernel<<<N_SUP / 4, 256, 0, stream>>>(s_feats, valid);
    prep_cnt_kernel<<<M_Q / 8, 256, 0, stream>>>(nbr, valid, rcnt);
    prep_wpack_kernel<<<(2 * NWAVES * KSP * 64 + 255) / 256, 256, 0, stream>>>(weights, wpack);

    const int grid = M_Q / QPB;
    if (use_bf) {
        kpconv_pass<0, true, false><<<grid, 256, 0, stream>>>(
            s_feats, featsbf, q_points, s_points, nbr, kpts, wpack, rcnt, bias, out, stats);
        kpconv_pass<1, true, true><<<grid, 256, 0, stream>>>(
            s_feats, featsbf, q_points, s_points, nbr, kpts, wpack, rcnt, bias, out, stats);
    } else {
        kpconv_pass<0, false, false><<<grid, 256, 0, stream>>>(
            s_feats, featsbf, q_points, s_points, nbr, kpts, wpack, rcnt, bias, out, stats);
        kpconv_pass<1, false, true><<<grid, 256, 0, stream>>>(
            s_feats, featsbf, q_points, s_points, nbr, kpts, wpack, rcnt, bias, out, stats);
    }
    gn_kernel<<<(M_Q * COUT / 4) / 256, 256, 0, stream>>>(stats, gamma, beta, out);
}